// Round 1
// baseline (21028.835 us; speedup 1.0000x reference)
//
#include <hip/hip_runtime.h>
#include <math.h>

#define MAX_LEN 128
#define NSYM    32000
#define HID     1024
#define BATCH   32

// ---------------------------------------------------------------------------
// Workspace layout (d_ws):
//   float              h_buf[2][BATCH][HID]        256 KB  (ping-pong hidden state)
//   unsigned long long slots[MAX_LEN][BATCH]        32 KB  (packed argmax per step)
// ---------------------------------------------------------------------------

__device__ __forceinline__ unsigned fkey(float x) {
    unsigned u = __float_as_uint(x);
    return (u & 0x80000000u) ? ~u : (u | 0x80000000u);  // monotonic float->uint
}

__global__ void init_slots(unsigned long long* slots) {
    int i = blockIdx.x * blockDim.x + threadIdx.x;
    if (i < MAX_LEN * BATCH) slots[i] = 0ULL;
}

// ---------------------------------------------------------------------------
// GRU gate kernel. grid = 256 x 256 threads. Block owns 4 h-columns.
// Thread: b = tid&31, j = (tid>>5)&3, s = tid>>7 (0: w_ih/x, 1: w_hh/h).
// LDS: w_t rows (24 x 128) linear (reads are 2-addr broadcasts per wave);
//      a_t [s][b][k] with float4-slot XOR swizzle (slot = kq ^ b) so the
//      batch-strided b128 reads are bank-even. All LDS traffic is b128.
// Per-(b,j) fmaf order identical to previous version (bit-identical h).
// ---------------------------------------------------------------------------
__global__ __launch_bounds__(256, 1) void gru_step(
    const float* __restrict__ h_in,
    const float* __restrict__ w_ih,
    const float* __restrict__ w_hh,
    const float* __restrict__ b_ih,
    const float* __restrict__ b_hh,
    const float* __restrict__ emb,
    const float* __restrict__ h_prev,
    float* __restrict__ h_next,
    const unsigned long long* __restrict__ slot_prev,
    int t)
{
    __shared__ float w_t[24][128];      // row = 12*s + 4*g + j
    __shared__ float a_t[2][32][128];   // [s][b][k], slot = kq ^ b
    __shared__ float s_gh[128][3];
    __shared__ int   s_tok[BATCH];

    const int tid = threadIdx.x;
    const int b   = tid & 31;
    const int j   = (tid >> 5) & 3;
    const int s   = tid >> 7;
    const int j0  = blockIdx.x * 4;

    if (tid < BATCH) {
        int tok;
        if (t == 0) tok = NSYM;  // BOS row
        else {
            unsigned long long sl = slot_prev[tid];
            tok = (int)(0xFFFFFFFFu - (unsigned)(sl & 0xFFFFFFFFull));
        }
        s_tok[tid] = tok;
    }
    __syncthreads();

    const float* hp = (t == 0) ? h_in : h_prev;

    float acc0 = 0.f, acc1 = 0.f, acc2 = 0.f;
    float4 pw[3], pa[8];

    // prefetch chunk 0 (global -> regs)
    {
        const int k0 = 0;
        #pragma unroll
        for (int i = 0; i < 3; ++i) {
            int f = tid + 256 * i;            // 0..767 (24 rows x 32 quads)
            int r = f >> 5, kq = f & 31;
            int rs = r / 12, rem = r % 12, g = rem >> 2, jx = rem & 3;
            const float* wsrc = rs ? w_hh : w_ih;
            pw[i] = *(const float4*)&wsrc[(size_t)(j0 + jx + 1024 * g) * HID + k0 + 4 * kq];
        }
        #pragma unroll
        for (int i = 0; i < 8; ++i) {
            int f = tid + 256 * i;            // 0..2047 (2 x 32 x 32 quads)
            int ss = f >> 10, bb = (f >> 5) & 31, kq = f & 31;
            const float* src = ss ? &hp[(size_t)bb * HID]
                                  : &emb[(size_t)s_tok[bb] * HID];
            pa[i] = *(const float4*)&src[k0 + 4 * kq];
        }
    }

    const float* wr0 = &w_t[12 * s + 0 + j][0];
    const float* wr1 = &w_t[12 * s + 4 + j][0];
    const float* wr2 = &w_t[12 * s + 8 + j][0];
    const float* arow = &a_t[s][b][0];

    for (int c = 0; c < 8; ++c) {
        __syncthreads();  // previous chunk's compute done
        #pragma unroll
        for (int i = 0; i < 3; ++i) {
            int f = tid + 256 * i;
            int r = f >> 5, kq = f & 31;
            *(float4*)&w_t[r][4 * kq] = pw[i];
        }
        #pragma unroll
        for (int i = 0; i < 8; ++i) {
            int f = tid + 256 * i;
            int ss = f >> 10, bb = (f >> 5) & 31, kq = f & 31;
            *(float4*)&a_t[ss][bb][4 * (kq ^ bb)] = pa[i];
        }
        __syncthreads();  // LDS ready

        if (c + 1 < 8) {
            const int k0 = (c + 1) * 128;
            #pragma unroll
            for (int i = 0; i < 3; ++i) {
                int f = tid + 256 * i;
                int r = f >> 5, kq = f & 31;
                int rs = r / 12, rem = r % 12, g = rem >> 2, jx = rem & 3;
                const float* wsrc = rs ? w_hh : w_ih;
                pw[i] = *(const float4*)&wsrc[(size_t)(j0 + jx + 1024 * g) * HID + k0 + 4 * kq];
            }
            #pragma unroll
            for (int i = 0; i < 8; ++i) {
                int f = tid + 256 * i;
                int ss = f >> 10, bb = (f >> 5) & 31, kq = f & 31;
                const float* src = ss ? &hp[(size_t)bb * HID]
                                      : &emb[(size_t)s_tok[bb] * HID];
                pa[i] = *(const float4*)&src[k0 + 4 * kq];
            }
        }

        #pragma unroll 8
        for (int q = 0; q < 32; ++q) {
            float4 av = *(const float4*)&arow[4 * (q ^ b)];
            float4 w0 = *(const float4*)&wr0[4 * q];
            float4 w1 = *(const float4*)&wr1[4 * q];
            float4 w2 = *(const float4*)&wr2[4 * q];
            acc0 = fmaf(av.x, w0.x, acc0); acc0 = fmaf(av.y, w0.y, acc0);
            acc0 = fmaf(av.z, w0.z, acc0); acc0 = fmaf(av.w, w0.w, acc0);
            acc1 = fmaf(av.x, w1.x, acc1); acc1 = fmaf(av.y, w1.y, acc1);
            acc1 = fmaf(av.z, w1.z, acc1); acc1 = fmaf(av.w, w1.w, acc1);
            acc2 = fmaf(av.x, w2.x, acc2); acc2 = fmaf(av.y, w2.y, acc2);
            acc2 = fmaf(av.z, w2.z, acc2); acc2 = fmaf(av.w, w2.w, acc2);
        }
    }

    __syncthreads();
    if (s == 1) {
        int pair = tid & 127;
        s_gh[pair][0] = acc0; s_gh[pair][1] = acc1; s_gh[pair][2] = acc2;
    }
    __syncthreads();
    if (s == 0) {
        int pair = tid & 127;
        int jg = j0 + j;
        float gir = acc0 + b_ih[jg];
        float giz = acc1 + b_ih[jg + 1024];
        float gin = acc2 + b_ih[jg + 2048];
        float ghr = s_gh[pair][0] + b_hh[jg];
        float ghz = s_gh[pair][1] + b_hh[jg + 1024];
        float ghn = s_gh[pair][2] + b_hh[jg + 2048];
        float r = 1.f / (1.f + expf(-(gir + ghr)));
        float z = 1.f / (1.f + expf(-(giz + ghz)));
        float n = tanhf(gin + r * ghn);
        float hv = hp[(size_t)b * HID + jg];
        h_next[(size_t)b * HID + jg] = (1.f - z) * n + z * hv;
    }
}

// ---------------------------------------------------------------------------
// Classifier kernel. grid = 250 x 256 threads, 32b x 128v tile, k-chunks of 64.
// b-on-lanes layout: bq = tid&15 (owns b=bq, bq+16), vg = tid>>4 (owns
// v = v0 + vg + 16*i, i<8). Per-wave w-reads are 4-address broadcasts; a-reads
// 16-address. XOR float4-slot swizzle (slot = kq ^ (row&15)) on both LDS
// buffers -> all b128, bank-even. Inner: 10 b128 + 64 FMA per 4kk (FMA-bound).
// Stores go through a 16 KB LDS transpose (reusing w_t) to stay coalesced.
// Per-(b,v) fmaf order identical to previous version (bit-identical logits).
// ---------------------------------------------------------------------------
__global__ __launch_bounds__(256, 1) void cls_step(
    const float* __restrict__ h_cur,
    const float* __restrict__ cls_w,
    const float* __restrict__ cls_b,
    float* __restrict__ out_t,
    unsigned long long* __restrict__ slot_t)
{
    __shared__ float w_t[128][64];   // [v_local][k], slot = kq ^ (v&15)
    __shared__ float a_t[32][64];    // [b][k],       slot = kq ^ (b&15)
    __shared__ unsigned long long s_best[BATCH];

    const int tid = threadIdx.x;
    const int bq  = tid & 15;
    const int vg  = tid >> 4;        // 0..15
    const int v0  = blockIdx.x * 128;

    if (tid < BATCH) s_best[tid] = 0ULL;

    float acc[2][8];
    #pragma unroll
    for (int h = 0; h < 2; ++h)
        #pragma unroll
        for (int i = 0; i < 8; ++i) acc[h][i] = 0.f;

    float4 pw[8], pa[2];

    // prefetch chunk 0
    {
        const int k0 = 0;
        #pragma unroll
        for (int i = 0; i < 8; ++i) {
            int f = tid + 256 * i;        // 0..2047 (128 rows x 16 quads)
            int v = f >> 4, kq = f & 15;
            pw[i] = *(const float4*)&cls_w[(size_t)(v0 + v) * HID + k0 + 4 * kq];
        }
        #pragma unroll
        for (int i = 0; i < 2; ++i) {
            int f = tid + 256 * i;        // 0..511 (32 rows x 16 quads)
            int bb = f >> 4, kq = f & 15;
            pa[i] = *(const float4*)&h_cur[(size_t)bb * HID + k0 + 4 * kq];
        }
    }

    for (int c = 0; c < 16; ++c) {
        __syncthreads();
        #pragma unroll
        for (int i = 0; i < 8; ++i) {
            int f = tid + 256 * i;
            int v = f >> 4, kq = f & 15;
            *(float4*)&w_t[v][4 * (kq ^ (v & 15))] = pw[i];
        }
        #pragma unroll
        for (int i = 0; i < 2; ++i) {
            int f = tid + 256 * i;
            int bb = f >> 4, kq = f & 15;
            *(float4*)&a_t[bb][4 * (kq ^ (bb & 15))] = pa[i];
        }
        __syncthreads();

        if (c + 1 < 16) {
            const int k0 = (c + 1) * 64;
            #pragma unroll
            for (int i = 0; i < 8; ++i) {
                int f = tid + 256 * i;
                int v = f >> 4, kq = f & 15;
                pw[i] = *(const float4*)&cls_w[(size_t)(v0 + v) * HID + k0 + 4 * kq];
            }
            #pragma unroll
            for (int i = 0; i < 2; ++i) {
                int f = tid + 256 * i;
                int bb = f >> 4, kq = f & 15;
                pa[i] = *(const float4*)&h_cur[(size_t)bb * HID + k0 + 4 * kq];
            }
        }

        #pragma unroll 4
        for (int q = 0; q < 16; ++q) {
            float4 a0 = *(const float4*)&a_t[bq][4 * (q ^ bq)];
            float4 a1 = *(const float4*)&a_t[bq + 16][4 * (q ^ bq)];
            #pragma unroll
            for (int i = 0; i < 8; ++i) {
                float4 wv = *(const float4*)&w_t[vg + 16 * i][4 * (q ^ vg)];
                acc[0][i] = fmaf(a0.x, wv.x, acc[0][i]);
                acc[0][i] = fmaf(a0.y, wv.y, acc[0][i]);
                acc[0][i] = fmaf(a0.z, wv.z, acc[0][i]);
                acc[0][i] = fmaf(a0.w, wv.w, acc[0][i]);
                acc[1][i] = fmaf(a1.x, wv.x, acc[1][i]);
                acc[1][i] = fmaf(a1.y, wv.y, acc[1][i]);
                acc[1][i] = fmaf(a1.z, wv.z, acc[1][i]);
                acc[1][i] = fmaf(a1.w, wv.w, acc[1][i]);
            }
        }
    }

    // epilogue: bias + fused argmax (packed), then LDS transpose -> coalesced store
    float vals[2][8];
    unsigned long long best0 = 0ULL, best1 = 0ULL;
    #pragma unroll
    for (int i = 0; i < 8; ++i) {
        int v = v0 + vg + 16 * i;
        float cb = cls_b[v];
        float x0 = acc[0][i] + cb;
        float x1 = acc[1][i] + cb;
        vals[0][i] = x0; vals[1][i] = x1;
        unsigned long long p0 = ((unsigned long long)fkey(x0) << 32) |
                                (unsigned long long)(0xFFFFFFFFu - (unsigned)v);
        unsigned long long p1 = ((unsigned long long)fkey(x1) << 32) |
                                (unsigned long long)(0xFFFFFFFFu - (unsigned)v);
        if (p0 > best0) best0 = p0;
        if (p1 > best1) best1 = p1;
    }
    atomicMax(&s_best[bq], best0);
    atomicMax(&s_best[bq + 16], best1);

    __syncthreads();                  // last chunk's w_t reads + s_best done
    float* trans = &w_t[0][0];        // 32 x 132 floats = 16.9 KB (fits in w_t)
    #pragma unroll
    for (int i = 0; i < 8; ++i) {
        trans[bq * 132 + vg + 16 * i]        = vals[0][i];
        trans[(bq + 16) * 132 + vg + 16 * i] = vals[1][i];
    }
    __syncthreads();
    #pragma unroll
    for (int it = 0; it < 4; ++it) {
        int idx = tid + 256 * it;     // 0..1023 (32 rows x 32 quads)
        int v4 = idx & 31, bb = idx >> 5;
        float4 o = *(const float4*)&trans[bb * 132 + 4 * v4];
        *(float4*)&out_t[(size_t)bb * NSYM + v0 + 4 * v4] = o;
    }
    if (tid < BATCH) atomicMax(&slot_t[tid], s_best[tid]);
}

// ---------------------------------------------------------------------------
extern "C" void kernel_launch(void* const* d_in, const int* in_sizes, int n_in,
                              void* d_out, int out_size, void* d_ws, size_t ws_size,
                              hipStream_t stream) {
    const float* h0    = (const float*)d_in[0];
    const float* w_ih  = (const float*)d_in[1];
    const float* w_hh  = (const float*)d_in[2];
    const float* b_ih  = (const float*)d_in[3];
    const float* b_hh  = (const float*)d_in[4];
    const float* cls_w = (const float*)d_in[5];
    const float* cls_b = (const float*)d_in[6];
    const float* emb   = (const float*)d_in[7];
    float* out = (float*)d_out;

    float* h_buf = (float*)d_ws;  // 2 * BATCH * HID floats
    unsigned long long* slots =
        (unsigned long long*)((char*)d_ws + (size_t)2 * BATCH * HID * sizeof(float));

    init_slots<<<16, 256, 0, stream>>>(slots);

    for (int t = 0; t < MAX_LEN; ++t) {
        float* h_prev = h_buf + (size_t)((t + 1) & 1) * BATCH * HID;
        float* h_next = h_buf + (size_t)(t & 1) * BATCH * HID;
        const unsigned long long* slot_prev = slots + (size_t)(t > 0 ? (t - 1) : 0) * BATCH;

        gru_step<<<256, 256, 0, stream>>>(h0, w_ih, w_hh, b_ih, b_hh, emb,
                                          h_prev, h_next, slot_prev, t);
        cls_step<<<250, 256, 0, stream>>>(h_next, cls_w, cls_b,
                                          out + (size_t)t * BATCH * NSYM,
                                          slots + (size_t)t * BATCH);
    }
}